// Round 14
// baseline (76.211 us; speedup 1.0000x reference)
//
#include <hip/hip_runtime.h>

// ---------------------------------------------------------------------------
// SlidingWindowAttention on MI355X (gfx950)
// B=2 T=2048 C=1024 H=16 D=64 WINDOW=256
// f16 16x16x32 MFMA. qkv: 2-wave 128x96 tile (wave-tile 64x96) -- LDS
// bytes/FLOP cut 19% (A read-amplification 2->1), grid 1024 all-resident.
// gemm_o: 64x64 tiles 4/CU; attn v5 + setprio; 2-D XCD L2 partition.
// ---------------------------------------------------------------------------

typedef _Float16 f16;
typedef _Float16 half8 __attribute__((ext_vector_type(8)));
typedef _Float16 half4 __attribute__((ext_vector_type(4)));
typedef float    f32x4 __attribute__((ext_vector_type(4)));

#define MFMA16(a, b, c) __builtin_amdgcn_mfma_f32_16x16x32_f16((a), (b), (c), 0, 0, 0)

__device__ __forceinline__ void gload16(const void* g, void* l) {
  __builtin_amdgcn_global_load_lds(
      (const __attribute__((address_space(1))) void*)g,
      (__attribute__((address_space(3))) void*)l, 16, 0, 0);
}

// ---------------------------------------------------------------------------
// prep v2: blocks 0..2047 convert x f32->f16 (8 elems/thread);
// blocks 2048..4095 transpose weights in 64(k) x 32(n) tiles.
__global__ __launch_bounds__(256) void prep_kernel(
    const float* __restrict__ x, f16* __restrict__ xb,
    const float* __restrict__ W0, const float* __restrict__ W1,
    const float* __restrict__ W2, const float* __restrict__ W3,
    f16* __restrict__ T0, f16* __restrict__ T1,
    f16* __restrict__ T2, f16* __restrict__ T3) {
  const int bid = blockIdx.x;
  if (bid < 2048) {
    const int idx = (bid * 256 + threadIdx.x) * 8;
    const float4 a = *(const float4*)(x + idx);
    const float4 b = *(const float4*)(x + idx + 4);
    half8 h;
    h[0] = (f16)a.x; h[1] = (f16)a.y; h[2] = (f16)a.z; h[3] = (f16)a.w;
    h[4] = (f16)b.x; h[5] = (f16)b.y; h[6] = (f16)b.z; h[7] = (f16)b.w;
    *(half8*)(xb + idx) = h;
    return;
  }
  __shared__ float tile[64][33];
  const int bid2 = bid - 2048;
  const int mat = bid2 >> 9;
  const int rem = bid2 & 511;
  const int kt = (rem >> 5) * 64;
  const int nt = (rem & 31) * 32;
  const float* W = mat == 0 ? W0 : mat == 1 ? W1 : mat == 2 ? W2 : W3;
  f16* T = mat == 0 ? T0 : mat == 1 ? T1 : mat == 2 ? T2 : T3;
  const int tid = threadIdx.x;
  const int r = tid >> 3;
  const int c4 = (tid & 7) * 4;
  const float4 v0 = *(const float4*)(W + (size_t)(kt + r) * 1024 + nt + c4);
  const float4 v1 = *(const float4*)(W + (size_t)(kt + r + 32) * 1024 + nt + c4);
  tile[r][c4 + 0] = v0.x; tile[r][c4 + 1] = v0.y;
  tile[r][c4 + 2] = v0.z; tile[r][c4 + 3] = v0.w;
  tile[r + 32][c4 + 0] = v1.x; tile[r + 32][c4 + 1] = v1.y;
  tile[r + 32][c4 + 2] = v1.z; tile[r + 32][c4 + 3] = v1.w;
  __syncthreads();
  const int n = tid >> 3;
  const int k8 = (tid & 7) * 8;
  half8 o;
  #pragma unroll
  for (int e = 0; e < 8; e++) o[e] = (f16)tile[k8 + e][n];
  *(half8*)(T + (size_t)(nt + n) * 1024 + kt + k8) = o;
}

// ---------------------------------------------------------------------------
// Fused QKV: 2-wave blocks (128 thr), tile 128(m) x 96(n), wave-tile 64x96.
// grid 1024 = 32m x 32n -> 4 blocks/CU, ALL resident. BK=64, LDS 28KB.
// Per K-step/wave: 14 gload16-half, 20 ds_read_b128, 48 MFMA (2.4:1).
// A read-amplification = 1 (each A row read by exactly one wave).
// 2-D XCD partition: 4(m) x 2(n) regions -> ~5 MB/XCD staging set.
__global__ __launch_bounds__(128, 2) void gemm_qkv_kernel(
    const f16* __restrict__ xb, const f16* __restrict__ wt,
    const float* __restrict__ bq, const float* __restrict__ bk,
    const float* __restrict__ bv,
    f16* __restrict__ qo, f16* __restrict__ ko, f16* __restrict__ vt) {
  __shared__ __align__(16) f16 As[128 * 64];
  __shared__ __align__(16) f16 Bs[96 * 64];
  const int xcd = blockIdx.x & 7;
  const int rr = blockIdx.x >> 3;                  // 0..127
  const int m0 = (((xcd & 3) * 8) + (rr & 7)) * 128;
  const int n0 = (((xcd >> 2) * 16) + (rr >> 3)) * 96;

  const int tid = threadIdx.x;
  const int lane = tid & 63, wave = tid >> 6;      // 2 waves
  const int fr = lane & 15, fg = lane >> 4;
  const int sx = (fr & 7) << 4;

  const int cc = lane & 7;
  const int srA = wave * 64 + (lane >> 3);         // A rows [w*64,+64), +t*8
  const int srB = wave * 48 + (lane >> 3);         // B rows [w*48,+48), +t*8
  const size_t goA = (size_t)srA * 1024 + (size_t)((cc ^ (srA & 7)) * 8);
  const size_t goB = (size_t)srB * 1024 + (size_t)((cc ^ (srB & 7)) * 8);
  const f16* ag = xb + (size_t)m0 * 1024 + goA;
  const f16* bg = wt + (size_t)n0 * 1024 + goB;
  f16* la = As + wave * 4096;                      // 64 rows * 64 elems
  f16* lb = Bs + wave * 3072;                      // 48 rows * 64 elems

  f32x4 acc[4][6];
  #pragma unroll
  for (int i = 0; i < 4; i++)
    #pragma unroll
    for (int j = 0; j < 6; j++) acc[i][j] = (f32x4){0.f, 0.f, 0.f, 0.f};

  for (int kt = 0; kt < 1024; kt += 64) {
    #pragma unroll
    for (int t = 0; t < 8; t++) gload16(ag + kt + t * 8192, la + t * 512);
    #pragma unroll
    for (int t = 0; t < 6; t++) gload16(bg + kt + t * 8192, lb + t * 512);
    __syncthreads();
    const char* Ab = (const char*)As;
    const char* Bb = (const char*)Bs;
    #pragma unroll
    for (int kk = 0; kk < 2; kk++) {
      half8 af[4], bf[6];
      const int co = (kk * 64 + fg * 16) ^ sx;
      #pragma unroll
      for (int mf = 0; mf < 4; mf++)
        af[mf] = *(const half8*)(Ab + (wave * 64 + mf * 16 + fr) * 128 + co);
      #pragma unroll
      for (int nf = 0; nf < 6; nf++)
        bf[nf] = *(const half8*)(Bb + (nf * 16 + fr) * 128 + co);
      #pragma unroll
      for (int mf = 0; mf < 4; mf++)
        #pragma unroll
        for (int nf = 0; nf < 6; nf++)
          acc[mf][nf] = MFMA16(af[mf], bf[nf], acc[mf][nf]);
    }
    __syncthreads();
  }

  // epilogue: 96-wide tile may span q/k/v boundaries; each 16-col fragment
  // stays within one matrix (boundaries are multiples of 16).
  #pragma unroll
  for (int nf = 0; nf < 6; nf++) {
    const int colg = n0 + nf * 16 + fr;
    const int mat = colg >> 10;
    const int c = colg & 1023;
    const float bb = (mat == 0 ? bq : mat == 1 ? bk : bv)[c];
    if (mat < 2) {
      f16* out = mat == 0 ? qo : ko;
      #pragma unroll
      for (int mf = 0; mf < 4; mf++)
        #pragma unroll
        for (int r = 0; r < 4; r++) {
          const int row = m0 + wave * 64 + mf * 16 + fg * 4 + r;
          out[(size_t)row * 1024 + c] = (f16)(acc[mf][nf][r] + bb);
        }
    } else {
      const int h = c >> 6, d = c & 63;
      #pragma unroll
      for (int mf = 0; mf < 4; mf++) {
        const int row = m0 + wave * 64 + mf * 16 + fg * 4;
        const int b = row >> 11, t = row & 2047;
        half4 vv;
        #pragma unroll
        for (int r = 0; r < 4; r++) vv[r] = (f16)(acc[mf][nf][r] + bb);
        *(half4*)(vt + (((size_t)(b * 16 + h)) * 64 + d) * 2048 + t) = vv;
      }
    }
  }
}

// ---------------------------------------------------------------------------
// Output projection v3: 64x64 tiles, grid 1024, 4 blocks/CU.
// 2-D XCD partition: 4(m) x 2(n) regions of 16 x 8 tiles -> 3 MB/XCD < L2.
__global__ __launch_bounds__(256, 4) void gemm_o_kernel(
    const f16* __restrict__ ao, const f16* __restrict__ wot,
    const float* __restrict__ bo, float* __restrict__ out) {
  __shared__ __align__(16) f16 As[64 * 64];
  __shared__ __align__(16) f16 Bs[64 * 64];
  const int xcd = blockIdx.x & 7;
  const int rr = blockIdx.x >> 3;                  // 0..127
  const int m0 = (((xcd & 3) * 16) + (rr & 15)) * 64;
  const int n0 = (((xcd >> 2) * 8) + (rr >> 4)) * 64;

  const int tid = threadIdx.x;
  const int lane = tid & 63, wave = tid >> 6;
  const int wm = wave >> 1, wn = wave & 1;
  const int fr = lane & 15, fg = lane >> 4;
  const int sx = (fr & 7) << 4;

  const int cc = lane & 7;
  const int srow = wave * 16 + (lane >> 3);
  const size_t go = (size_t)srow * 1024 + (size_t)((cc ^ (srow & 7)) * 8);
  const f16* ag = ao + (size_t)m0 * 1024 + go;
  const f16* bg = wot + (size_t)n0 * 1024 + go;
  f16* la = As + wave * 1024;
  f16* lb = Bs + wave * 1024;

  f32x4 acc[2][2];
  #pragma unroll
  for (int i = 0; i < 2; i++)
    #pragma unroll
    for (int j = 0; j < 2; j++) acc[i][j] = (f32x4){0.f, 0.f, 0.f, 0.f};

  for (int kt = 0; kt < 1024; kt += 64) {
    #pragma unroll
    for (int t = 0; t < 2; t++) {
      gload16(ag + kt + t * 8192, la + t * 512);
      gload16(bg + kt + t * 8192, lb + t * 512);
    }
    __syncthreads();
    const char* Ab = (const char*)As;
    const char* Bb = (const char*)Bs;
    #pragma unroll
    for (int kk = 0; kk < 2; kk++) {
      half8 af[2], bf[2];
      const int co = (kk * 64 + fg * 16) ^ sx;
      #pragma unroll
      for (int mf = 0; mf < 2; mf++)
        af[mf] = *(const half8*)(Ab + (wm * 32 + mf * 16 + fr) * 128 + co);
      #pragma unroll
      for (int nf = 0; nf < 2; nf++)
        bf[nf] = *(const half8*)(Bb + (wn * 32 + nf * 16 + fr) * 128 + co);
      #pragma unroll
      for (int mf = 0; mf < 2; mf++)
        #pragma unroll
        for (int nf = 0; nf < 2; nf++)
          acc[mf][nf] = MFMA16(af[mf], bf[nf], acc[mf][nf]);
    }
    __syncthreads();
  }

  #pragma unroll
  for (int mf = 0; mf < 2; mf++)
    #pragma unroll
    for (int nf = 0; nf < 2; nf++) {
      const int col = n0 + wn * 32 + nf * 16 + fr;
      const float bb = bo[col];
      #pragma unroll
      for (int r = 0; r < 4; r++) {
        const int row = m0 + wm * 32 + mf * 16 + fg * 4 + r;
        out[(size_t)row * 1024 + col] = acc[mf][nf][r] + bb;
      }
    }
}

// ---------------------------------------------------------------------------
// Sliding-window attention v5 + setprio: QBLK=128, KVBLK=64, XCD-clustered bh.
// Swapped QK^T -> P assembled in registers; PV in permuted key order.
__global__ __launch_bounds__(256, 3) void attn_kernel(
    const f16* __restrict__ Q, const f16* __restrict__ K,
    const f16* __restrict__ Vt, f16* __restrict__ Ao) {
  __shared__ __align__(16) f16 Ks[2][64 * 64];
  __shared__ __align__(16) f16 Vs[2][64 * 64];

  const int tid = threadIdx.x, lane = tid & 63, wave = tid >> 6;
  const int fr = lane & 15, g = lane >> 4;
  const int wg = (blockIdx.x & 7) * 64 + (blockIdx.x >> 3);
  const int qt = wg & 15, bh = wg >> 4;
  const int b = bh >> 4, h = bh & 15;
  const int q0 = qt * 128;
  const int qr = q0 + wave * 32;

  const f16* Qb = Q + ((size_t)(b * 2048 + qr)) * 1024 + h * 64;
  half8 qf[2][2];
  #pragma unroll
  for (int mc = 0; mc < 2; mc++)
    #pragma unroll
    for (int kk = 0; kk < 2; kk++)
      qf[mc][kk] =
          *(const half8*)(Qb + (size_t)(mc * 16 + fr) * 1024 + kk * 32 + g * 8);

  const char* Kg = (const char*)(K + ((size_t)(b * 2048)) * 1024 + h * 64);
  const char* Vg = (const char*)(Vt + ((size_t)(b * 16 + h)) * 64 * 2048);

  const int sr = wave * 16 + (lane >> 3);
  const int sco = ((lane & 7) ^ (sr & 7)) << 4;

  auto stageKV = [&](int buf, int jt) {
    #pragma unroll
    for (int t = 0; t < 2; t++) {
      gload16(Kg + (size_t)(jt + sr + t * 8) * 2048 + sco,
              (f16*)Ks[buf] + wave * 1024 + t * 512);
      gload16(Vg + (size_t)(sr + t * 8) * 4096 + (size_t)jt * 2 + sco,
              (f16*)Vs[buf] + wave * 1024 + t * 512);
    }
  };

  const int t0 = q0 >= 256 ? (q0 - 256) >> 6 : 0;
  const int t1 = (q0 + 127) >> 6;

  f32x4 O[2][4];
  #pragma unroll
  for (int mc = 0; mc < 2; mc++)
    #pragma unroll
    for (int nt = 0; nt < 4; nt++) O[mc][nt] = (f32x4){0.f, 0.f, 0.f, 0.f};
  float lsum[2] = {0.f, 0.f};

  stageKV(0, t0 * 64);
  __syncthreads();

  for (int tt = t0; tt <= t1; ++tt) {
    const int cur = (tt - t0) & 1;
    if (tt < t1) stageKV(cur ^ 1, (tt + 1) * 64);
    const int jt = tt * 64;
    const bool alive = (jt <= qr + 31) && (jt + 63 >= qr - 256);
    if (alive) {
      const char* Kb = (const char*)Ks[cur];
      const char* Vb = (const char*)Vs[cur];
      half8 pa[2][2];
      #pragma unroll
      for (int jj = 0; jj < 4; ++jj) {
        const int kj = jj * 16 + fr;
        const char* krow = Kb + kj * 128;
        const int kswz = (kj & 7) << 4;
        const half8 kf0 = *(const half8*)(krow + ((g * 16) ^ kswz));
        const half8 kf1 = *(const half8*)(krow + ((64 + g * 16) ^ kswz));
        #pragma unroll
        for (int mc = 0; mc < 2; ++mc) {
          f32x4 z = (f32x4){0.f, 0.f, 0.f, 0.f};
          __builtin_amdgcn_s_setprio(1);
          z = MFMA16(kf0, qf[mc][0], z);
          z = MFMA16(kf1, qf[mc][1], z);
          __builtin_amdgcn_s_setprio(0);
          const int eb = qr + mc * 16 + fr - jt - jj * 16 - g * 4;
          #pragma unroll
          for (int r = 0; r < 4; ++r) {
            const float a = __expf(z[r] * 0.125f - 3.0f);
            const float p = ((unsigned)(eb - r) <= 256u) ? a : 0.f;
            lsum[mc] += p;
            pa[mc][jj >> 1][(jj & 1) * 4 + r] = (f16)p;
          }
        }
      }
      __builtin_amdgcn_s_setprio(1);
      #pragma unroll
      for (int ks = 0; ks < 2; ++ks) {
        #pragma unroll
        for (int nt = 0; nt < 4; ++nt) {
          const int vd = nt * 16 + fr;
          const int sw = (vd & 7) << 4;
          const half4 vlo =
              *(const half4*)(Vb + vd * 128 + ((ks * 64 + 8 * g) ^ sw));
          const half4 vhi =
              *(const half4*)(Vb + vd * 128 + ((ks * 64 + 32 + 8 * g) ^ sw));
          half8 vf;
          vf[0] = vlo[0]; vf[1] = vlo[1]; vf[2] = vlo[2]; vf[3] = vlo[3];
          vf[4] = vhi[0]; vf[5] = vhi[1]; vf[6] = vhi[2]; vf[7] = vhi[3];
          O[0][nt] = MFMA16(pa[0][ks], vf, O[0][nt]);
          O[1][nt] = MFMA16(pa[1][ks], vf, O[1][nt]);
        }
      }
      __builtin_amdgcn_s_setprio(0);
    }
    __syncthreads();
  }

  float inv[2][4];
  #pragma unroll
  for (int mc = 0; mc < 2; ++mc) {
    float t = lsum[mc];
    t += __shfl_xor(t, 16);
    t += __shfl_xor(t, 32);
    #pragma unroll
    for (int r = 0; r < 4; ++r) inv[mc][r] = 1.0f / __shfl(t, g * 4 + r);
  }
  f16* Aout = Ao + ((size_t)(b * 2048 + qr)) * 1024 + h * 64;
  #pragma unroll
  for (int mc = 0; mc < 2; ++mc)
    #pragma unroll
    for (int nt = 0; nt < 4; ++nt)
      #pragma unroll
      for (int r = 0; r < 4; ++r)
        Aout[(size_t)(mc * 16 + g * 4 + r) * 1024 + nt * 16 + fr] =
            (f16)(O[mc][nt][r] * inv[mc][r]);
}

// ---------------------------------------------------------------------------
extern "C" void kernel_launch(void* const* d_in, const int* in_sizes, int n_in,
                              void* d_out, int out_size, void* d_ws,
                              size_t ws_size, hipStream_t stream) {
  const float* x  = (const float*)d_in[0];
  const float* Wq = (const float*)d_in[1];
  const float* bq = (const float*)d_in[2];
  const float* Wk = (const float*)d_in[3];
  const float* bk = (const float*)d_in[4];
  const float* Wv = (const float*)d_in[5];
  const float* bv = (const float*)d_in[6];
  const float* Wo = (const float*)d_in[7];
  const float* bo = (const float*)d_in[8];

  char* w = (char*)d_ws;
  f16* xb  = (f16*)(w);                          // 8 MiB  : x in f16
  f16* wqt = (f16*)(w + ((size_t)8 << 20));      // 2 MiB  : Wq^T f16
  f16* wkt = (f16*)(w + ((size_t)10 << 20));     //        (wq/wk/wv contiguous)
  f16* wvt = (f16*)(w + ((size_t)12 << 20));
  f16* wot = (f16*)(w + ((size_t)14 << 20));
  f16* q   = (f16*)(w + ((size_t)16 << 20));     // 8 MiB  : Q [4096][1024]
  f16* kk  = (f16*)(w + ((size_t)24 << 20));     // 8 MiB  : K
  f16* vt  = (f16*)(w + ((size_t)32 << 20));     // 8 MiB  : V^T [b][h][d][t]
  f16* ao  = (f16*)(w + ((size_t)40 << 20));     // 8 MiB  : attn out

  prep_kernel<<<4096, 256, 0, stream>>>(x, xb, Wq, Wk, Wv, Wo,
                                        wqt, wkt, wvt, wot);
  gemm_qkv_kernel<<<1024, 128, 0, stream>>>(xb, wqt, bq, bk, bv, q, kk, vt);
  attn_kernel<<<512, 256, 0, stream>>>(q, kk, vt, ao);
  gemm_o_kernel<<<1024, 256, 0, stream>>>(ao, wot, bo, (float*)d_out);
}

// Round 15
// 73.715 us; speedup vs baseline: 1.0339x; 1.0339x over previous
//
#include <hip/hip_runtime.h>

// ---------------------------------------------------------------------------
// SlidingWindowAttention on MI355X (gfx950)  -- round-12 best config restore
// B=2 T=2048 C=1024 H=16 D=64 WINDOW=256
// f16 16x16x32 MFMA. qkv: 4-wave 128x128 2-barrier core, grid 768, 2-D XCD
// L2 partition; gemm_o: 64x64 tiles grid 1024 (4 blocks/CU); attn v5 +
// setprio (swapped QK^T, in-register P); prep v2.
// ---------------------------------------------------------------------------

typedef _Float16 f16;
typedef _Float16 half8 __attribute__((ext_vector_type(8)));
typedef _Float16 half4 __attribute__((ext_vector_type(4)));
typedef float    f32x4 __attribute__((ext_vector_type(4)));

#define MFMA16(a, b, c) __builtin_amdgcn_mfma_f32_16x16x32_f16((a), (b), (c), 0, 0, 0)

__device__ __forceinline__ void gload16(const void* g, void* l) {
  __builtin_amdgcn_global_load_lds(
      (const __attribute__((address_space(1))) void*)g,
      (__attribute__((address_space(3))) void*)l, 16, 0, 0);
}

// ---------------------------------------------------------------------------
// prep v2: blocks 0..2047 convert x f32->f16 (8 elems/thread);
// blocks 2048..4095 transpose weights in 64(k) x 32(n) tiles.
__global__ __launch_bounds__(256) void prep_kernel(
    const float* __restrict__ x, f16* __restrict__ xb,
    const float* __restrict__ W0, const float* __restrict__ W1,
    const float* __restrict__ W2, const float* __restrict__ W3,
    f16* __restrict__ T0, f16* __restrict__ T1,
    f16* __restrict__ T2, f16* __restrict__ T3) {
  const int bid = blockIdx.x;
  if (bid < 2048) {
    const int idx = (bid * 256 + threadIdx.x) * 8;
    const float4 a = *(const float4*)(x + idx);
    const float4 b = *(const float4*)(x + idx + 4);
    half8 h;
    h[0] = (f16)a.x; h[1] = (f16)a.y; h[2] = (f16)a.z; h[3] = (f16)a.w;
    h[4] = (f16)b.x; h[5] = (f16)b.y; h[6] = (f16)b.z; h[7] = (f16)b.w;
    *(half8*)(xb + idx) = h;
    return;
  }
  __shared__ float tile[64][33];
  const int bid2 = bid - 2048;
  const int mat = bid2 >> 9;
  const int rem = bid2 & 511;
  const int kt = (rem >> 5) * 64;
  const int nt = (rem & 31) * 32;
  const float* W = mat == 0 ? W0 : mat == 1 ? W1 : mat == 2 ? W2 : W3;
  f16* T = mat == 0 ? T0 : mat == 1 ? T1 : mat == 2 ? T2 : T3;
  const int tid = threadIdx.x;
  const int r = tid >> 3;
  const int c4 = (tid & 7) * 4;
  const float4 v0 = *(const float4*)(W + (size_t)(kt + r) * 1024 + nt + c4);
  const float4 v1 = *(const float4*)(W + (size_t)(kt + r + 32) * 1024 + nt + c4);
  tile[r][c4 + 0] = v0.x; tile[r][c4 + 1] = v0.y;
  tile[r][c4 + 2] = v0.z; tile[r][c4 + 3] = v0.w;
  tile[r + 32][c4 + 0] = v1.x; tile[r + 32][c4 + 1] = v1.y;
  tile[r + 32][c4 + 2] = v1.z; tile[r + 32][c4 + 3] = v1.w;
  __syncthreads();
  const int n = tid >> 3;
  const int k8 = (tid & 7) * 8;
  half8 o;
  #pragma unroll
  for (int e = 0; e < 8; e++) o[e] = (f16)tile[k8 + e][n];
  *(half8*)(T + (size_t)(nt + n) * 1024 + kt + k8) = o;
}

// ---------------------------------------------------------------------------
// 4-wave 128x128 GEMM core: wave tile 64x64, BK=64, 16 K-steps.
__device__ __forceinline__ void gemm_core4(const f16* __restrict__ A,
                                           const f16* __restrict__ Bt,
                                           int m0, int n0,
                                           f16* As, f16* Bs,
                                           f32x4 acc[4][4]) {
  const int tid = threadIdx.x;
  const int lane = tid & 63, wave = tid >> 6;
  const int wm = wave >> 1, wn = wave & 1;
  const int fr = lane & 15, fg = lane >> 4;
  const int sx = (fr & 7) << 4;

  const int srow = wave * 32 + (lane >> 3);
  const int cc = lane & 7;
  const size_t go = (size_t)srow * 1024 + (size_t)((cc ^ (srow & 7)) * 8);
  const f16* ag = A + (size_t)m0 * 1024 + go;
  const f16* bg = Bt + (size_t)n0 * 1024 + go;
  f16* la = As + wave * 2048;
  f16* lb = Bs + wave * 2048;

  #pragma unroll
  for (int i = 0; i < 4; i++)
    #pragma unroll
    for (int j = 0; j < 4; j++) acc[i][j] = (f32x4){0.f, 0.f, 0.f, 0.f};

  for (int kt = 0; kt < 1024; kt += 64) {
    #pragma unroll
    for (int t = 0; t < 4; t++) {
      gload16(ag + kt + t * 8192, la + t * 512);
      gload16(bg + kt + t * 8192, lb + t * 512);
    }
    __syncthreads();
    const char* Ab = (const char*)As;
    const char* Bb = (const char*)Bs;
    #pragma unroll
    for (int kk = 0; kk < 2; kk++) {
      half8 af[4], bf[4];
      const int co = (kk * 64 + fg * 16) ^ sx;
      #pragma unroll
      for (int mf = 0; mf < 4; mf++)
        af[mf] = *(const half8*)(Ab + (wm * 64 + mf * 16 + fr) * 128 + co);
      #pragma unroll
      for (int nf = 0; nf < 4; nf++)
        bf[nf] = *(const half8*)(Bb + (wn * 64 + nf * 16 + fr) * 128 + co);
      #pragma unroll
      for (int mf = 0; mf < 4; mf++)
        #pragma unroll
        for (int nf = 0; nf < 4; nf++)
          acc[mf][nf] = MFMA16(af[mf], bf[nf], acc[mf][nf]);
    }
    __syncthreads();
  }
}

// ---------------------------------------------------------------------------
// Fused QKV: grid 768, 256 threads, 3 blocks/CU.
// 2-D XCD partition: 8 XCDs as 4(m) x 2(n) regions of 8 m-tiles x 12 n-tiles
// -> per-XCD staging set 2 MB A + 3 MB B (fits L2).
__global__ __launch_bounds__(256, 3) void gemm_qkv_kernel(
    const f16* __restrict__ xb, const f16* __restrict__ wt,
    const float* __restrict__ bq, const float* __restrict__ bk,
    const float* __restrict__ bv,
    f16* __restrict__ qo, f16* __restrict__ ko, f16* __restrict__ vt) {
  __shared__ __align__(16) f16 As[128 * 64];
  __shared__ __align__(16) f16 Bs[128 * 64];
  const int xcd = blockIdx.x & 7;
  const int rr = blockIdx.x >> 3;                  // 0..95
  const int m0 = (((xcd & 3) * 8) + (rr & 7)) * 128;
  const int n0 = (((xcd >> 2) * 12) + (rr >> 3)) * 128;
  f32x4 acc[4][4];
  gemm_core4(xb, wt, m0, n0, As, Bs, acc);

  const int lane = threadIdx.x & 63, wave = threadIdx.x >> 6;
  const int wm = wave >> 1, wn = wave & 1;
  const int fr = lane & 15, fg = lane >> 4;
  const int matid = n0 >> 10;
  const int nc0 = n0 & 1023;
  const float* bias = matid == 0 ? bq : matid == 1 ? bk : bv;
  if (matid < 2) {
    f16* out = matid == 0 ? qo : ko;
    #pragma unroll
    for (int mf = 0; mf < 4; mf++)
      #pragma unroll
      for (int nf = 0; nf < 4; nf++) {
        const int col = nc0 + wn * 64 + nf * 16 + fr;
        const float bb = bias[col];
        #pragma unroll
        for (int r = 0; r < 4; r++) {
          const int row = m0 + wm * 64 + mf * 16 + fg * 4 + r;
          out[(size_t)row * 1024 + col] = (f16)(acc[mf][nf][r] + bb);
        }
      }
  } else {
    #pragma unroll
    for (int mf = 0; mf < 4; mf++)
      #pragma unroll
      for (int nf = 0; nf < 4; nf++) {
        const int row = m0 + wm * 64 + mf * 16 + fg * 4;
        const int col = nc0 + wn * 64 + nf * 16 + fr;
        const int b = row >> 11, t = row & 2047;
        const int h = col >> 6, d = col & 63;
        const float bb = bias[col];
        half4 vv;
        #pragma unroll
        for (int r = 0; r < 4; r++) vv[r] = (f16)(acc[mf][nf][r] + bb);
        *(half4*)(vt + (((size_t)(b * 16 + h)) * 64 + d) * 2048 + t) = vv;
      }
  }
}

// ---------------------------------------------------------------------------
// Output projection v3: 64x64 tiles, grid 1024, 4 blocks/CU.
// 2-D XCD partition: 4(m) x 2(n) regions of 16 x 8 tiles -> 3 MB/XCD < L2.
__global__ __launch_bounds__(256, 4) void gemm_o_kernel(
    const f16* __restrict__ ao, const f16* __restrict__ wot,
    const float* __restrict__ bo, float* __restrict__ out) {
  __shared__ __align__(16) f16 As[64 * 64];
  __shared__ __align__(16) f16 Bs[64 * 64];
  const int xcd = blockIdx.x & 7;
  const int rr = blockIdx.x >> 3;                  // 0..127
  const int m0 = (((xcd & 3) * 16) + (rr & 15)) * 64;
  const int n0 = (((xcd >> 2) * 8) + (rr >> 4)) * 64;

  const int tid = threadIdx.x;
  const int lane = tid & 63, wave = tid >> 6;
  const int wm = wave >> 1, wn = wave & 1;
  const int fr = lane & 15, fg = lane >> 4;
  const int sx = (fr & 7) << 4;

  const int cc = lane & 7;
  const int srow = wave * 16 + (lane >> 3);
  const size_t go = (size_t)srow * 1024 + (size_t)((cc ^ (srow & 7)) * 8);
  const f16* ag = ao + (size_t)m0 * 1024 + go;
  const f16* bg = wot + (size_t)n0 * 1024 + go;
  f16* la = As + wave * 1024;
  f16* lb = Bs + wave * 1024;

  f32x4 acc[2][2];
  #pragma unroll
  for (int i = 0; i < 2; i++)
    #pragma unroll
    for (int j = 0; j < 2; j++) acc[i][j] = (f32x4){0.f, 0.f, 0.f, 0.f};

  for (int kt = 0; kt < 1024; kt += 64) {
    #pragma unroll
    for (int t = 0; t < 2; t++) {
      gload16(ag + kt + t * 8192, la + t * 512);
      gload16(bg + kt + t * 8192, lb + t * 512);
    }
    __syncthreads();
    const char* Ab = (const char*)As;
    const char* Bb = (const char*)Bs;
    #pragma unroll
    for (int kk = 0; kk < 2; kk++) {
      half8 af[2], bf[2];
      const int co = (kk * 64 + fg * 16) ^ sx;
      #pragma unroll
      for (int mf = 0; mf < 2; mf++)
        af[mf] = *(const half8*)(Ab + (wm * 32 + mf * 16 + fr) * 128 + co);
      #pragma unroll
      for (int nf = 0; nf < 2; nf++)
        bf[nf] = *(const half8*)(Bb + (wn * 32 + nf * 16 + fr) * 128 + co);
      #pragma unroll
      for (int mf = 0; mf < 2; mf++)
        #pragma unroll
        for (int nf = 0; nf < 2; nf++)
          acc[mf][nf] = MFMA16(af[mf], bf[nf], acc[mf][nf]);
    }
    __syncthreads();
  }

  #pragma unroll
  for (int mf = 0; mf < 2; mf++)
    #pragma unroll
    for (int nf = 0; nf < 2; nf++) {
      const int col = n0 + wn * 32 + nf * 16 + fr;
      const float bb = bo[col];
      #pragma unroll
      for (int r = 0; r < 4; r++) {
        const int row = m0 + wm * 32 + mf * 16 + fg * 4 + r;
        out[(size_t)row * 1024 + col] = acc[mf][nf][r] + bb;
      }
    }
}

// ---------------------------------------------------------------------------
// Sliding-window attention v5 + setprio: QBLK=128, KVBLK=64, XCD-clustered bh.
// Swapped QK^T -> P assembled in registers; PV in permuted key order.
__global__ __launch_bounds__(256, 3) void attn_kernel(
    const f16* __restrict__ Q, const f16* __restrict__ K,
    const f16* __restrict__ Vt, f16* __restrict__ Ao) {
  __shared__ __align__(16) f16 Ks[2][64 * 64];
  __shared__ __align__(16) f16 Vs[2][64 * 64];

  const int tid = threadIdx.x, lane = tid & 63, wave = tid >> 6;
  const int fr = lane & 15, g = lane >> 4;
  const int wg = (blockIdx.x & 7) * 64 + (blockIdx.x >> 3);
  const int qt = wg & 15, bh = wg >> 4;
  const int b = bh >> 4, h = bh & 15;
  const int q0 = qt * 128;
  const int qr = q0 + wave * 32;

  const f16* Qb = Q + ((size_t)(b * 2048 + qr)) * 1024 + h * 64;
  half8 qf[2][2];
  #pragma unroll
  for (int mc = 0; mc < 2; mc++)
    #pragma unroll
    for (int kk = 0; kk < 2; kk++)
      qf[mc][kk] =
          *(const half8*)(Qb + (size_t)(mc * 16 + fr) * 1024 + kk * 32 + g * 8);

  const char* Kg = (const char*)(K + ((size_t)(b * 2048)) * 1024 + h * 64);
  const char* Vg = (const char*)(Vt + ((size_t)(b * 16 + h)) * 64 * 2048);

  const int sr = wave * 16 + (lane >> 3);
  const int sco = ((lane & 7) ^ (sr & 7)) << 4;

  auto stageKV = [&](int buf, int jt) {
    #pragma unroll
    for (int t = 0; t < 2; t++) {
      gload16(Kg + (size_t)(jt + sr + t * 8) * 2048 + sco,
              (f16*)Ks[buf] + wave * 1024 + t * 512);
      gload16(Vg + (size_t)(sr + t * 8) * 4096 + (size_t)jt * 2 + sco,
              (f16*)Vs[buf] + wave * 1024 + t * 512);
    }
  };

  const int t0 = q0 >= 256 ? (q0 - 256) >> 6 : 0;
  const int t1 = (q0 + 127) >> 6;

  f32x4 O[2][4];
  #pragma unroll
  for (int mc = 0; mc < 2; mc++)
    #pragma unroll
    for (int nt = 0; nt < 4; nt++) O[mc][nt] = (f32x4){0.f, 0.f, 0.f, 0.f};
  float lsum[2] = {0.f, 0.f};

  stageKV(0, t0 * 64);
  __syncthreads();

  for (int tt = t0; tt <= t1; ++tt) {
    const int cur = (tt - t0) & 1;
    if (tt < t1) stageKV(cur ^ 1, (tt + 1) * 64);
    const int jt = tt * 64;
    const bool alive = (jt <= qr + 31) && (jt + 63 >= qr - 256);
    if (alive) {
      const char* Kb = (const char*)Ks[cur];
      const char* Vb = (const char*)Vs[cur];
      half8 pa[2][2];
      #pragma unroll
      for (int jj = 0; jj < 4; ++jj) {
        const int kj = jj * 16 + fr;
        const char* krow = Kb + kj * 128;
        const int kswz = (kj & 7) << 4;
        const half8 kf0 = *(const half8*)(krow + ((g * 16) ^ kswz));
        const half8 kf1 = *(const half8*)(krow + ((64 + g * 16) ^ kswz));
        #pragma unroll
        for (int mc = 0; mc < 2; ++mc) {
          f32x4 z = (f32x4){0.f, 0.f, 0.f, 0.f};
          __builtin_amdgcn_s_setprio(1);
          z = MFMA16(kf0, qf[mc][0], z);
          z = MFMA16(kf1, qf[mc][1], z);
          __builtin_amdgcn_s_setprio(0);
          const int eb = qr + mc * 16 + fr - jt - jj * 16 - g * 4;
          #pragma unroll
          for (int r = 0; r < 4; ++r) {
            const float a = __expf(z[r] * 0.125f - 3.0f);
            const float p = ((unsigned)(eb - r) <= 256u) ? a : 0.f;
            lsum[mc] += p;
            pa[mc][jj >> 1][(jj & 1) * 4 + r] = (f16)p;
          }
        }
      }
      __builtin_amdgcn_s_setprio(1);
      #pragma unroll
      for (int ks = 0; ks < 2; ++ks) {
        #pragma unroll
        for (int nt = 0; nt < 4; ++nt) {
          const int vd = nt * 16 + fr;
          const int sw = (vd & 7) << 4;
          const half4 vlo =
              *(const half4*)(Vb + vd * 128 + ((ks * 64 + 8 * g) ^ sw));
          const half4 vhi =
              *(const half4*)(Vb + vd * 128 + ((ks * 64 + 32 + 8 * g) ^ sw));
          half8 vf;
          vf[0] = vlo[0]; vf[1] = vlo[1]; vf[2] = vlo[2]; vf[3] = vlo[3];
          vf[4] = vhi[0]; vf[5] = vhi[1]; vf[6] = vhi[2]; vf[7] = vhi[3];
          O[0][nt] = MFMA16(pa[0][ks], vf, O[0][nt]);
          O[1][nt] = MFMA16(pa[1][ks], vf, O[1][nt]);
        }
      }
      __builtin_amdgcn_s_setprio(0);
    }
    __syncthreads();
  }

  float inv[2][4];
  #pragma unroll
  for (int mc = 0; mc < 2; ++mc) {
    float t = lsum[mc];
    t += __shfl_xor(t, 16);
    t += __shfl_xor(t, 32);
    #pragma unroll
    for (int r = 0; r < 4; ++r) inv[mc][r] = 1.0f / __shfl(t, g * 4 + r);
  }
  f16* Aout = Ao + ((size_t)(b * 2048 + qr)) * 1024 + h * 64;
  #pragma unroll
  for (int mc = 0; mc < 2; ++mc)
    #pragma unroll
    for (int nt = 0; nt < 4; ++nt)
      #pragma unroll
      for (int r = 0; r < 4; ++r)
        Aout[(size_t)(mc * 16 + g * 4 + r) * 1024 + nt * 16 + fr] =
            (f16)(O[mc][nt][r] * inv[mc][r]);
}

// ---------------------------------------------------------------------------
extern "C" void kernel_launch(void* const* d_in, const int* in_sizes, int n_in,
                              void* d_out, int out_size, void* d_ws,
                              size_t ws_size, hipStream_t stream) {
  const float* x  = (const float*)d_in[0];
  const float* Wq = (const float*)d_in[1];
  const float* bq = (const float*)d_in[2];
  const float* Wk = (const float*)d_in[3];
  const float* bk = (const float*)d_in[4];
  const float* Wv = (const float*)d_in[5];
  const float* bv = (const float*)d_in[6];
  const float* Wo = (const float*)d_in[7];
  const float* bo = (const float*)d_in[8];

  char* w = (char*)d_ws;
  f16* xb  = (f16*)(w);                          // 8 MiB  : x in f16
  f16* wqt = (f16*)(w + ((size_t)8 << 20));      // 2 MiB  : Wq^T f16
  f16* wkt = (f16*)(w + ((size_t)10 << 20));     //        (wq/wk/wv contiguous)
  f16* wvt = (f16*)(w + ((size_t)12 << 20));
  f16* wot = (f16*)(w + ((size_t)14 << 20));
  f16* q   = (f16*)(w + ((size_t)16 << 20));     // 8 MiB  : Q [4096][1024]
  f16* kk  = (f16*)(w + ((size_t)24 << 20));     // 8 MiB  : K
  f16* vt  = (f16*)(w + ((size_t)32 << 20));     // 8 MiB  : V^T [b][h][d][t]
  f16* ao  = (f16*)(w + ((size_t)40 << 20));     // 8 MiB  : attn out

  prep_kernel<<<4096, 256, 0, stream>>>(x, xb, Wq, Wk, Wv, Wo,
                                        wqt, wkt, wvt, wot);
  gemm_qkv_kernel<<<768, 256, 0, stream>>>(xb, wqt, bq, bk, bv, q, kk, vt);
  attn_kernel<<<512, 256, 0, stream>>>(q, kk, vt, ao);
  gemm_o_kernel<<<1024, 256, 0, stream>>>(ao, wot, bo, (float*)d_out);
}